// Round 9
// baseline (680.126 us; speedup 1.0000x reference)
//
#include <hip/hip_runtime.h>

#define B_   4
#define T_   2048
#define BT_  8192
#define INL  15
#define DM   256
#define DI   512
#define DX   1024
#define DS_  16
#define DR_  16
#define NO_  48
#define NL   4
#define NC_  128
#define LCH  16

typedef short bf16x8 __attribute__((ext_vector_type(8)));
typedef float f32x4  __attribute__((ext_vector_type(4)));

__device__ __forceinline__ float sigmoidf_(float x){ return 1.f/(1.f+__expf(-x)); }

__device__ __forceinline__ unsigned short f2bf(float x){
    union { float f; unsigned u; } v; v.f = x;
    unsigned r = (v.u + 0x7FFFu + ((v.u >> 16) & 1u)) >> 16;
    return (unsigned short)r;
}
__device__ __forceinline__ float bf2f(unsigned short h){
    union { unsigned u; float f; } v; v.u = ((unsigned)h) << 16;
    return v.f;
}

__device__ __forceinline__ void ld16(const float* __restrict__ p, float* v){
    const float4* q = (const float4*)p;
    float4 x0=q[0],x1=q[1],x2=q[2],x3=q[3];
    v[0]=x0.x; v[1]=x0.y; v[2]=x0.z; v[3]=x0.w;
    v[4]=x1.x; v[5]=x1.y; v[6]=x1.z; v[7]=x1.w;
    v[8]=x2.x; v[9]=x2.y; v[10]=x2.z; v[11]=x2.w;
    v[12]=x3.x; v[13]=x3.y; v[14]=x3.z; v[15]=x3.w;
}
__device__ __forceinline__ void st16(float* __restrict__ p, const float* v){
    float4* q = (float4*)p;
    q[0] = make_float4(v[0],v[1],v[2],v[3]);
    q[1] = make_float4(v[4],v[5],v[6],v[7]);
    q[2] = make_float4(v[8],v[9],v[10],v[11]);
    q[3] = make_float4(v[12],v[13],v[14],v[15]);
}

// convert fp32 array -> bf16 hi/lo split
__global__ void k_cvtW(const float* __restrict__ W, unsigned short* __restrict__ hi,
                       unsigned short* __restrict__ lo, int n4){
    int g = blockIdx.x*256 + threadIdx.x;
    if(g >= n4) return;
    float4 v = ((const float4*)W)[g];
    ushort4 h, l;
    h.x = f2bf(v.x); l.x = f2bf(v.x - bf2f(h.x));
    h.y = f2bf(v.y); l.y = f2bf(v.y - bf2f(h.y));
    h.z = f2bf(v.z); l.z = f2bf(v.z - bf2f(h.z));
    h.w = f2bf(v.w); l.w = f2bf(v.w - bf2f(h.w));
    ((ushort4*)hi)[g] = h;
    ((ushort4*)lo)[g] = l;
}

// h[bt][m] = sum_k x[bt][k] * in_W[m][k]
__global__ void k_ingemm(const float* __restrict__ x, const float* __restrict__ W,
                         float* __restrict__ h){
    int g  = blockIdx.x*256 + threadIdx.x;
    int bt = g >> 8, m = g & 255;
    const float* xr = x + bt*INL;
    const float* wr = W + m*INL;
    float acc = 0.f;
#pragma unroll
    for(int k=0;k<INL;k++) acc += xr[k]*wr[k];
    h[g] = acc;
}

// res = h (+ res_prev); hn = LN(res)*w+b -> bf16 hi/lo  (layer 0 only)
__global__ void k_resln(const float* __restrict__ h, float* __restrict__ res,
                        unsigned short* __restrict__ hnhi, unsigned short* __restrict__ hnlo,
                        const float* __restrict__ w, const float* __restrict__ b, int addRes){
    int wv = threadIdx.x >> 6, lane = threadIdx.x & 63;
    int bt = blockIdx.x*4 + wv;
    float4 v = ((const float4*)(h + (size_t)bt*DM))[lane];
    if(addRes){
        float4 r = ((const float4*)(res + (size_t)bt*DM))[lane];
        v.x+=r.x; v.y+=r.y; v.z+=r.z; v.w+=r.w;
    }
    ((float4*)(res + (size_t)bt*DM))[lane] = v;
    float s  = v.x+v.y+v.z+v.w;
    float ss = v.x*v.x+v.y*v.y+v.z*v.z+v.w*v.w;
#pragma unroll
    for(int m=1;m<64;m<<=1){ s += __shfl_xor(s,m); ss += __shfl_xor(ss,m); }
    float mean = s*(1.f/DM);
    float var  = ss*(1.f/DM) - mean*mean;
    float inv  = rsqrtf(var + 1e-5f);
    float4 wt = ((const float4*)w)[lane];
    float4 bs = ((const float4*)b)[lane];
    float4 o;
    o.x = (v.x-mean)*inv*wt.x + bs.x;
    o.y = (v.y-mean)*inv*wt.y + bs.y;
    o.z = (v.z-mean)*inv*wt.z + bs.z;
    o.w = (v.w-mean)*inv*wt.w + bs.w;
    ushort4 hh, ll;
    hh.x = f2bf(o.x); ll.x = f2bf(o.x - bf2f(hh.x));
    hh.y = f2bf(o.y); ll.y = f2bf(o.y - bf2f(hh.y));
    hh.z = f2bf(o.z); ll.z = f2bf(o.z - bf2f(hh.z));
    hh.w = f2bf(o.w); ll.w = f2bf(o.w - bf2f(hh.w));
    ((ushort4*)(hnhi + (size_t)bt*DM))[lane] = hh;
    ((ushort4*)(hnlo + (size_t)bt*DM))[lane] = ll;
}

// C[M][N] = A[M][K] @ Bw[N][K]^T via bf16 MFMA, hi/lo 3-term split (inproj)
template<int BM,int BN>
__global__ void __launch_bounds__(256) k_gemm_bf3(
    const unsigned short* __restrict__ Ahi, const unsigned short* __restrict__ Alo,
    const unsigned short* __restrict__ Bhi, const unsigned short* __restrict__ Blo,
    float* __restrict__ C, int M, int N, int K)
{
    constexpr int LDP = 40;
    constexpr int WM = BM/2, WN = BN/2;
    constexpr int MI_ = WM/16, NI_ = WN/16;
    __shared__ unsigned short sAh[BM*LDP], sAl[BM*LDP], sBh[BN*LDP], sBl[BN*LDP];
    int tid  = threadIdx.x;
    int wave = tid >> 6, lane = tid & 63;
    int wm0  = (wave >> 1) * WM, wn0 = (wave & 1) * WN;
    int m0   = blockIdx.y * BM, n0 = blockIdx.x * BN;
    int lr   = lane & 15;
    int kq   = (lane >> 4) * 8;
    int quad4 = (lane >> 4) * 4;

    f32x4 acc[MI_][NI_];
#pragma unroll
    for(int i=0;i<MI_;i++)
#pragma unroll
        for(int j=0;j<NI_;j++) acc[i][j] = (f32x4){0.f,0.f,0.f,0.f};

    for(int k0=0;k0<K;k0+=32){
#pragma unroll
        for(int i=tid;i<BM*4;i+=256){
            int r = i>>2, cg = (i&3)*8;
            size_t go = (size_t)(m0+r)*K + k0 + cg;
            *(float4*)(&sAh[r*LDP + cg]) = *(const float4*)(Ahi + go);
            *(float4*)(&sAl[r*LDP + cg]) = *(const float4*)(Alo + go);
        }
#pragma unroll
        for(int i=tid;i<BN*4;i+=256){
            int r = i>>2, cg = (i&3)*8;
            size_t go = (size_t)(n0+r)*K + k0 + cg;
            *(float4*)(&sBh[r*LDP + cg]) = *(const float4*)(Bhi + go);
            *(float4*)(&sBl[r*LDP + cg]) = *(const float4*)(Blo + go);
        }
        __syncthreads();
        bf16x8 ah[MI_], al[MI_], bh[NI_], bl[NI_];
#pragma unroll
        for(int mi=0;mi<MI_;mi++){
            int ro = (wm0 + mi*16 + lr)*LDP + kq;
            ah[mi] = *(const bf16x8*)(&sAh[ro]);
            al[mi] = *(const bf16x8*)(&sAl[ro]);
        }
#pragma unroll
        for(int ni=0;ni<NI_;ni++){
            int ro = (wn0 + ni*16 + lr)*LDP + kq;
            bh[ni] = *(const bf16x8*)(&sBh[ro]);
            bl[ni] = *(const bf16x8*)(&sBl[ro]);
        }
#pragma unroll
        for(int mi=0;mi<MI_;mi++)
#pragma unroll
            for(int ni=0;ni<NI_;ni++){
                acc[mi][ni] = __builtin_amdgcn_mfma_f32_16x16x32_bf16(ah[mi], bh[ni], acc[mi][ni], 0,0,0);
                acc[mi][ni] = __builtin_amdgcn_mfma_f32_16x16x32_bf16(ah[mi], bl[ni], acc[mi][ni], 0,0,0);
                acc[mi][ni] = __builtin_amdgcn_mfma_f32_16x16x32_bf16(al[mi], bh[ni], acc[mi][ni], 0,0,0);
            }
        __syncthreads();
    }
#pragma unroll
    for(int mi=0;mi<MI_;mi++)
#pragma unroll
        for(int ni=0;ni<NI_;ni++){
            int col = n0 + wn0 + ni*16 + lr;
#pragma unroll
            for(int r=0;r<4;r++){
                int row = m0 + wm0 + mi*16 + quad4 + r;
                C[(size_t)row*N + col] = acc[mi][ni][r];
            }
        }
}

// ---- conv+SiLU | xproj MFMA | dtproj (scan-1 split out) ----
__global__ void __launch_bounds__(512) k_convxp2(
    const float* __restrict__ xz, const float* __restrict__ cw, const float* __restrict__ cb,
    const unsigned short* __restrict__ Bhi, const unsigned short* __restrict__ Blo,
    const float* __restrict__ dtW, const float* __restrict__ dtbias,
    float* __restrict__ xh, float* __restrict__ bc, float* __restrict__ dtO)
{
    __shared__ unsigned short sAh[16*520], sAl[16*520];
    __shared__ float dls[16*17];

    int tid = threadIdx.x;
    int wave = tid >> 6, lane = tid & 63;
    int lr = lane & 15, kq = (lane>>4)*8, quad4 = (lane>>4)*4;
    int m0 = blockIdx.x * LCH;
    int d  = tid;

    // phase A: conv + SiLU
    float xv[19];
    {
        int rbase = m0 - 3;
        bool mask0 = ((m0 & (T_-1)) == 0);
#pragma unroll
        for(int j=0;j<19;j++)
            xv[j] = (mask0 && j<3) ? 0.f : xz[(size_t)(rbase+j)*DX + d];
    }
    float4 w4 = *(const float4*)(cw + d*4);
    float bias = cb[d];
#pragma unroll
    for(int t=0;t<16;t++){
        float a = bias + w4.x*xv[t] + w4.y*xv[t+1] + w4.z*xv[t+2] + w4.w*xv[t+3];
        float v = a * sigmoidf_(a);
        xh[(size_t)(m0+t)*DI + d] = v;
        unsigned short hh = f2bf(v);
        sAh[t*520 + d] = hh;
        sAl[t*520 + d] = f2bf(v - bf2f(hh));
    }
    float wr_[16]; ld16(dtW + (size_t)d*16, wr_);
    float bsv = dtbias[d];
    __syncthreads();

    // phase B: xproj MFMA, waves 0-2 = n-tiles, B streamed from L2
    f32x4 acc = {0.f,0.f,0.f,0.f};
    if(wave < 3){
#pragma unroll 4
        for(int ks=0;ks<16;ks++){
            int ao = lr*520 + ks*32 + kq;
            bf16x8 ah = *(const bf16x8*)(&sAh[ao]);
            bf16x8 al = *(const bf16x8*)(&sAl[ao]);
            size_t wo = (size_t)(wave*16 + lr)*DI + ks*32 + kq;
            bf16x8 bh = *(const bf16x8*)(Bhi + wo);
            bf16x8 bl = *(const bf16x8*)(Blo + wo);
            acc = __builtin_amdgcn_mfma_f32_16x16x32_bf16(ah, bh, acc, 0,0,0);
            acc = __builtin_amdgcn_mfma_f32_16x16x32_bf16(ah, bl, acc, 0,0,0);
            acc = __builtin_amdgcn_mfma_f32_16x16x32_bf16(al, bh, acc, 0,0,0);
        }
        if(wave == 0){
#pragma unroll
            for(int r=0;r<4;r++) dls[(quad4+r)*17 + lr] = acc[r];
        } else if(wave == 1){
#pragma unroll
            for(int r=0;r<4;r++) bc[(size_t)(m0+quad4+r)*32 + lr] = acc[r];
        } else {
#pragma unroll
            for(int r=0;r<4;r++) bc[(size_t)(m0+quad4+r)*32 + 16 + lr] = acc[r];
        }
    }
    __syncthreads();

    // phase C: dtproj + softplus
#pragma unroll
    for(int t=0;t<16;t++){
        float acc2 = bsv;
#pragma unroll
        for(int r=0;r<16;r++) acc2 += dls[t*17 + r]*wr_[r];
        float sp = fmaxf(acc2,0.f) + log1pf(__expf(-fabsf(acc2)));
        dtO[(size_t)(m0+t)*DI + d] = sp;
    }
}

// ---- scan pass-1: standalone, grid (2, NC, B) = 1024 blocks ----
__global__ void __launch_bounds__(256) k_scan1(const float* __restrict__ dt,
    const float* __restrict__ xh, const float* __restrict__ bc,
    const float* __restrict__ A_log, float* __restrict__ S, float* __restrict__ sdt){
    int d = blockIdx.x*256 + threadIdx.x;
    int c = blockIdx.y, b = blockIdx.z;
    float a_[16]; ld16(A_log + (size_t)d*16, a_);
#pragma unroll
    for(int n=0;n<16;n++) a_[n] = -__expf(a_[n]);
    float st_[16];
#pragma unroll
    for(int n=0;n<16;n++) st_[n] = 0.f;
    float sd = 0.f;
    int base = b*T_ + c*LCH;
#pragma unroll 4
    for(int t=0;t<LCH;t++){
        int bt = base + t;
        float dtv = dt[(size_t)bt*DI + d];
        float xhv = xh[(size_t)bt*DI + d];
        float bv[16]; ld16(bc + (size_t)bt*32, bv);
        float dx = dtv*xhv;
        sd += dtv;
#pragma unroll
        for(int n=0;n<16;n++) st_[n] = __expf(dtv*a_[n])*st_[n] + dx*bv[n];
    }
    st16(S + (((size_t)b*NC_ + c)*DI + d)*16, st_);
    sdt[((size_t)b*NC_ + c)*DI + d] = sd;
}

// ---- pass 2: inter-chunk scan ----
__global__ void k_scan2(const float* __restrict__ S, const float* __restrict__ sdt,
                        const float* __restrict__ A_log, float* __restrict__ Hinit){
    int g = blockIdx.x*256 + threadIdx.x;
    int b = g >> 13;
    int dn = g & 8191;
    int d = dn >> 4;
    float a = -__expf(A_log[dn]);
    float H = 0.f;
    for(int c=0;c<NC_;c++){
        size_t o = ((size_t)(b*NC_ + c))*8192 + dn;
        Hinit[o] = H;
        float sd = sdt[(size_t)(b*NC_ + c)*DI + d];
        H = __expf(sd*a)*H + S[o];
    }
}

// ---- scan pass-3: replay + gate, d-split grid (2, NC, B) = 1024 blocks ----
__global__ void __launch_bounds__(256) k_scan3(
    const float* __restrict__ dt, const float* __restrict__ xh, const float* __restrict__ xz,
    const float* __restrict__ bc, const float* __restrict__ A_log, const float* __restrict__ Dpar,
    const float* __restrict__ Hinit, unsigned* __restrict__ Y)
{
    __shared__ float sbc[16*36];
    int tid = threadIdx.x;
    int c = blockIdx.y, b = blockIdx.z;
    int m0 = b*T_ + c*LCH;
    if(tid < 128){
        int t = tid >> 3, s = tid & 7;
        *(float4*)(&sbc[t*36 + s*4]) = *(const float4*)(bc + (size_t)(m0+t)*32 + s*4);
    }
    __syncthreads();
    int d = blockIdx.x*256 + tid;
    float a_[16]; ld16(A_log + (size_t)d*16, a_);
#pragma unroll
    for(int n=0;n<16;n++) a_[n] = -__expf(a_[n]);
    float st_[16]; ld16(Hinit + (((size_t)b*NC_ + c)*DI + d)*16, st_);
    float Dp = Dpar[d];
#pragma unroll 4
    for(int t=0;t<LCH;t++){
        int bt = m0 + t;
        float dtv = dt[(size_t)bt*DI + d];
        float xhv = xh[(size_t)bt*DI + d];
        float bv[16]; ld16(&sbc[t*36], bv);
        float cv[16]; ld16(&sbc[t*36 + 16], cv);
        float dx = dtv*xhv;
        float y = 0.f;
#pragma unroll
        for(int n=0;n<16;n++){
            st_[n] = __expf(dtv*a_[n])*st_[n] + dx*bv[n];
            y += st_[n]*cv[n];
        }
        float zv = xz[(size_t)bt*DX + DI + d];
        y += Dp*xhv;
        y = y * zv * sigmoidf_(zv);
        unsigned short hh = f2bf(y);
        unsigned short ll = f2bf(y - bf2f(hh));
        Y[(size_t)bt*DI + d] = (unsigned)hh | ((unsigned)ll << 16);
    }
}

// ---- outproj GEMM (BM=64, BN=256) + fused residual + LN + bf16 split ----
__global__ void __launch_bounds__(256) k_outln(
    const unsigned* __restrict__ Y, const unsigned short* __restrict__ Bhi,
    const unsigned short* __restrict__ Blo, float* __restrict__ res,
    const float* __restrict__ nw, const float* __restrict__ nb,
    unsigned short* __restrict__ hnhi, unsigned short* __restrict__ hnlo,
    float* __restrict__ hOut, int last)
{
    __shared__ __align__(16) char smem[66560];
    unsigned short* sAh = (unsigned short*)smem;       // 64*40
    unsigned short* sAl = sAh + 64*40;
    unsigned short* sBh = sAl + 64*40;                 // 256*40
    unsigned short* sBl = sBh + 256*40;
    float* sC = (float*)smem;                          // 64*260 (phase 2)

    int tid = threadIdx.x;
    int wave = tid >> 6, lane = tid & 63;
    int wm0 = (wave >> 1)*32, wn0 = (wave & 1)*128;
    int m0 = blockIdx.x*64;
    int lr = lane & 15, kq = (lane>>4)*8, quad4 = (lane>>4)*4;

    f32x4 acc[2][8];
#pragma unroll
    for(int i=0;i<2;i++)
#pragma unroll
        for(int j=0;j<8;j++) acc[i][j] = (f32x4){0.f,0.f,0.f,0.f};

    for(int k0=0;k0<DI;k0+=32){
        {
            int r = tid>>2, s = tid&3;
            const uint4* yp = (const uint4*)(Y + (size_t)(m0+r)*DI + k0 + s*8);
            uint4 p0 = yp[0], p1 = yp[1];
            union { bf16x8 v; unsigned short u[8]; } H, L;
            H.u[0]=(unsigned short)p0.x; L.u[0]=(unsigned short)(p0.x>>16);
            H.u[1]=(unsigned short)p0.y; L.u[1]=(unsigned short)(p0.y>>16);
            H.u[2]=(unsigned short)p0.z; L.u[2]=(unsigned short)(p0.z>>16);
            H.u[3]=(unsigned short)p0.w; L.u[3]=(unsigned short)(p0.w>>16);
            H.u[4]=(unsigned short)p1.x; L.u[4]=(unsigned short)(p1.x>>16);
            H.u[5]=(unsigned short)p1.y; L.u[5]=(unsigned short)(p1.y>>16);
            H.u[6]=(unsigned short)p1.z; L.u[6]=(unsigned short)(p1.z>>16);
            H.u[7]=(unsigned short)p1.w; L.u[7]=(unsigned short)(p1.w>>16);
            *(bf16x8*)(&sAh[r*40 + s*8]) = H.v;
            *(bf16x8*)(&sAl[r*40 + s*8]) = L.v;
        }
#pragma unroll
        for(int i=tid;i<1024;i+=256){
            int r = i>>2, s = i&3;
            size_t go = (size_t)r*DI + k0 + s*8;
            *(float4*)(&sBh[r*40 + s*8]) = *(const float4*)(Bhi + go);
            *(float4*)(&sBl[r*40 + s*8]) = *(const float4*)(Blo + go);
        }
        __syncthreads();
        bf16x8 ah[2], al[2];
#pragma unroll
        for(int mi=0;mi<2;mi++){
            int ro = (wm0 + mi*16 + lr)*40 + kq;
            ah[mi] = *(const bf16x8*)(&sAh[ro]);
            al[mi] = *(const bf16x8*)(&sAl[ro]);
        }
#pragma unroll
        for(int ni=0;ni<8;ni++){
            int ro = (wn0 + ni*16 + lr)*40 + kq;
            bf16x8 bh = *(const bf16x8*)(&sBh[ro]);
            bf16x8 bl = *(const bf16x8*)(&sBl[ro]);
#pragma unroll
            for(int mi=0;mi<2;mi++){
                acc[mi][ni] = __builtin_amdgcn_mfma_f32_16x16x32_bf16(ah[mi], bh, acc[mi][ni], 0,0,0);
                acc[mi][ni] = __builtin_amdgcn_mfma_f32_16x16x32_bf16(ah[mi], bl, acc[mi][ni], 0,0,0);
                acc[mi][ni] = __builtin_amdgcn_mfma_f32_16x16x32_bf16(al[mi], bh, acc[mi][ni], 0,0,0);
            }
        }
        __syncthreads();
    }
#pragma unroll
    for(int mi=0;mi<2;mi++)
#pragma unroll
        for(int ni=0;ni<8;ni++){
            int col = wn0 + ni*16 + lr;
#pragma unroll
            for(int r=0;r<4;r++)
                sC[(wm0 + mi*16 + quad4 + r)*260 + col] = acc[mi][ni][r];
        }
    __syncthreads();
    float4 wt, bs;
    if(!last){
        wt = ((const float4*)nw)[lane];
        bs = ((const float4*)nb)[lane];
    }
    for(int j=0;j<16;j++){
        int row = wave*16 + j;
        int gr  = m0 + row;
        float4 cv = *(float4*)(&sC[row*260 + lane*4]);
        if(last){
            ((float4*)(hOut + (size_t)gr*DM))[lane] = cv;
            continue;
        }
        float4 rv = ((const float4*)(res + (size_t)gr*DM))[lane];
        cv.x+=rv.x; cv.y+=rv.y; cv.z+=rv.z; cv.w+=rv.w;
        ((float4*)(res + (size_t)gr*DM))[lane] = cv;
        float s  = cv.x+cv.y+cv.z+cv.w;
        float ss = cv.x*cv.x+cv.y*cv.y+cv.z*cv.z+cv.w*cv.w;
#pragma unroll
        for(int m=1;m<64;m<<=1){ s += __shfl_xor(s,m); ss += __shfl_xor(ss,m); }
        float mean = s*(1.f/DM);
        float var  = ss*(1.f/DM) - mean*mean;
        float inv  = rsqrtf(var + 1e-5f);
        float4 o;
        o.x = (cv.x-mean)*inv*wt.x + bs.x;
        o.y = (cv.y-mean)*inv*wt.y + bs.y;
        o.z = (cv.z-mean)*inv*wt.z + bs.z;
        o.w = (cv.w-mean)*inv*wt.w + bs.w;
        ushort4 hh, ll;
        hh.x = f2bf(o.x); ll.x = f2bf(o.x - bf2f(hh.x));
        hh.y = f2bf(o.y); ll.y = f2bf(o.y - bf2f(hh.y));
        hh.z = f2bf(o.z); ll.z = f2bf(o.z - bf2f(hh.z));
        hh.w = f2bf(o.w); ll.w = f2bf(o.w - bf2f(hh.w));
        ((ushort4*)(hnhi + (size_t)gr*DM))[lane] = hh;
        ((ushort4*)(hnlo + (size_t)gr*DM))[lane] = ll;
    }
}

// out[bt] = dot(h[bt, :256], out_W)
__global__ void k_outw(const float* __restrict__ h, const float* __restrict__ ow,
                       float* __restrict__ out){
    int wv = threadIdx.x >> 6, lane = threadIdx.x & 63;
    int bt = blockIdx.x*4 + wv;
    float4 v = ((const float4*)(h + (size_t)bt*DM))[lane];
    float4 w = ((const float4*)ow)[lane];
    float s = v.x*w.x + v.y*w.y + v.z*w.z + v.w*w.w;
#pragma unroll
    for(int m=1;m<64;m<<=1) s += __shfl_xor(s,m);
    if(lane==0) out[bt] = s;
}

extern "C" void kernel_launch(void* const* d_in, const int* in_sizes, int n_in,
                              void* d_out, int out_size, void* d_ws, size_t ws_size,
                              hipStream_t stream){
    const float* x_src    = (const float*)d_in[0];
    const float* in_W     = (const float*)d_in[2];
    const float* norm_w   = (const float*)d_in[3];
    const float* norm_b   = (const float*)d_in[4];
    const float* inproj_W = (const float*)d_in[5];
    const float* conv_w   = (const float*)d_in[6];
    const float* conv_b   = (const float*)d_in[7];
    const float* xproj_W  = (const float*)d_in[8];
    const float* dtproj_W = (const float*)d_in[9];
    const float* dtproj_b = (const float*)d_in[10];
    const float* A_log    = (const float*)d_in[11];
    const float* D_param  = (const float*)d_in[12];
    const float* outproj_W= (const float*)d_in[13];
    const float* out_W    = (const float*)d_in[14];

    float* ws  = (float*)d_ws;
    float* h    = ws;                        // BT*DM
    float* res  = h    + (size_t)BT_*DM;     // BT*DM
    float* xz   = res  + (size_t)BT_*DM;     // BT*DX
    float* xh   = xz   + (size_t)BT_*DX;     // BT*DI
    float* bcb  = xh   + (size_t)BT_*DI;     // BT*32
    float* dtb  = bcb  + (size_t)BT_*32;     // BT*DI
    float* sdtb = dtb  + (size_t)BT_*DI;     // B*NC*DI
    float* Sbuf = sdtb + (size_t)B_*NC_*DI;  // B*NC*DI*16
    float* Hbuf = Sbuf + (size_t)B_*NC_*DI*DS_;
    unsigned short* us = (unsigned short*)(Hbuf + (size_t)B_*NC_*DI*DS_);
    unsigned short* WhiIn  = us;                                  // NL*DX*DM
    unsigned short* WloIn  = WhiIn  + (size_t)NL*DX*DM;
    unsigned short* WhiOut = WloIn  + (size_t)NL*DX*DM;           // NL*DM*DI
    unsigned short* WloOut = WhiOut + (size_t)NL*DM*DI;
    unsigned short* WhiXp  = WloOut + (size_t)NL*DM*DI;           // NL*NO*DI
    unsigned short* WloXp  = WhiXp  + (size_t)NL*NO_*DI;
    unsigned short* hnhi   = WloXp  + (size_t)NL*NO_*DI;          // BT*DM
    unsigned short* hnlo   = hnhi   + (size_t)BT_*DM;
    unsigned*       ybuf   = (unsigned*)(hnlo + (size_t)BT_*DM);  // BT*DI

    k_cvtW<<<(NL*DX*DM/4 + 255)/256, 256, 0, stream>>>(inproj_W,  WhiIn,  WloIn,  NL*DX*DM/4);
    k_cvtW<<<(NL*DM*DI/4 + 255)/256, 256, 0, stream>>>(outproj_W, WhiOut, WloOut, NL*DM*DI/4);
    k_cvtW<<<(NL*NO_*DI/4 + 255)/256, 256, 0, stream>>>(xproj_W, WhiXp, WloXp, NL*NO_*DI/4);
    k_ingemm<<<BT_*DM/256, 256, 0, stream>>>(x_src, in_W, h);
    k_resln<<<BT_/4, 256, 0, stream>>>(h, res, hnhi, hnlo, norm_w, norm_b, 0);
    for(int i=0;i<NL;i++){
        k_gemm_bf3<128,128><<<dim3(DX/128, BT_/128), 256, 0, stream>>>(
            hnhi, hnlo, WhiIn + (size_t)i*DX*DM, WloIn + (size_t)i*DX*DM, xz, BT_, DX, DM);
        k_convxp2<<<BT_/LCH, 512, 0, stream>>>(xz, conv_w + i*DI*4, conv_b + i*DI,
            WhiXp + (size_t)i*NO_*DI, WloXp + (size_t)i*NO_*DI,
            dtproj_W + (size_t)i*DI*DR_, dtproj_b + i*DI, xh, bcb, dtb);
        k_scan1<<<dim3(2, NC_, B_), 256, 0, stream>>>(dtb, xh, bcb,
            A_log + (size_t)i*DI*DS_, Sbuf, sdtb);
        k_scan2<<<B_*DI*DS_/256, 256, 0, stream>>>(Sbuf, sdtb, A_log + (size_t)i*DI*DS_, Hbuf);
        k_scan3<<<dim3(2, NC_, B_), 256, 0, stream>>>(dtb, xh, xz, bcb, A_log + (size_t)i*DI*DS_,
            D_param + i*DI, Hbuf, ybuf);
        int last = (i == NL-1) ? 1 : 0;
        const float* nw = last ? norm_w : (norm_w + (i+1)*DM);
        const float* nb = last ? norm_b : (norm_b + (i+1)*DM);
        k_outln<<<BT_/64, 256, 0, stream>>>(ybuf, WhiOut + (size_t)i*DM*DI, WloOut + (size_t)i*DM*DI,
            res, nw, nb, hnhi, hnlo, h, last);
    }
    k_outw<<<BT_/4, 256, 0, stream>>>(h, out_W, (float*)d_out);
}

// Round 10
// 622.248 us; speedup vs baseline: 1.0930x; 1.0930x over previous
//
#include <hip/hip_runtime.h>

#define B_   4
#define T_   2048
#define BT_  8192
#define INL  15
#define DM   256
#define DI   512
#define DX   1024
#define DS_  16
#define DR_  16
#define NO_  48
#define NL   4
#define NC_  128
#define LCH  16

typedef short bf16x8 __attribute__((ext_vector_type(8)));
typedef float f32x4  __attribute__((ext_vector_type(4)));

__device__ __forceinline__ float sigmoidf_(float x){ return 1.f/(1.f+__expf(-x)); }

__device__ __forceinline__ unsigned short f2bf(float x){
    union { float f; unsigned u; } v; v.f = x;
    unsigned r = (v.u + 0x7FFFu + ((v.u >> 16) & 1u)) >> 16;
    return (unsigned short)r;
}
__device__ __forceinline__ float bf2f(unsigned short h){
    union { unsigned u; float f; } v; v.u = ((unsigned)h) << 16;
    return v.f;
}

__device__ __forceinline__ void ld16(const float* __restrict__ p, float* v){
    const float4* q = (const float4*)p;
    float4 x0=q[0],x1=q[1],x2=q[2],x3=q[3];
    v[0]=x0.x; v[1]=x0.y; v[2]=x0.z; v[3]=x0.w;
    v[4]=x1.x; v[5]=x1.y; v[6]=x1.z; v[7]=x1.w;
    v[8]=x2.x; v[9]=x2.y; v[10]=x2.z; v[11]=x2.w;
    v[12]=x3.x; v[13]=x3.y; v[14]=x3.z; v[15]=x3.w;
}
__device__ __forceinline__ void st16(float* __restrict__ p, const float* v){
    float4* q = (float4*)p;
    q[0] = make_float4(v[0],v[1],v[2],v[3]);
    q[1] = make_float4(v[4],v[5],v[6],v[7]);
    q[2] = make_float4(v[8],v[9],v[10],v[11]);
    q[3] = make_float4(v[12],v[13],v[14],v[15]);
}

// convert fp32 array -> bf16 hi/lo split
__global__ void k_cvtW(const float* __restrict__ W, unsigned short* __restrict__ hi,
                       unsigned short* __restrict__ lo, int n4){
    int g = blockIdx.x*256 + threadIdx.x;
    if(g >= n4) return;
    float4 v = ((const float4*)W)[g];
    ushort4 h, l;
    h.x = f2bf(v.x); l.x = f2bf(v.x - bf2f(h.x));
    h.y = f2bf(v.y); l.y = f2bf(v.y - bf2f(h.y));
    h.z = f2bf(v.z); l.z = f2bf(v.z - bf2f(h.z));
    h.w = f2bf(v.w); l.w = f2bf(v.w - bf2f(h.w));
    ((ushort4*)hi)[g] = h;
    ((ushort4*)lo)[g] = l;
}

// h[bt][m] = sum_k x[bt][k] * in_W[m][k]
__global__ void k_ingemm(const float* __restrict__ x, const float* __restrict__ W,
                         float* __restrict__ h){
    int g  = blockIdx.x*256 + threadIdx.x;
    int bt = g >> 8, m = g & 255;
    const float* xr = x + bt*INL;
    const float* wr = W + m*INL;
    float acc = 0.f;
#pragma unroll
    for(int k=0;k<INL;k++) acc += xr[k]*wr[k];
    h[g] = acc;
}

// res = h (+ res_prev); hn = LN(res)*w+b -> bf16 hi/lo
__global__ void k_resln(const float* __restrict__ h, float* __restrict__ res,
                        unsigned short* __restrict__ hnhi, unsigned short* __restrict__ hnlo,
                        const float* __restrict__ w, const float* __restrict__ b, int addRes){
    int wv = threadIdx.x >> 6, lane = threadIdx.x & 63;
    int bt = blockIdx.x*4 + wv;
    float4 v = ((const float4*)(h + (size_t)bt*DM))[lane];
    if(addRes){
        float4 r = ((const float4*)(res + (size_t)bt*DM))[lane];
        v.x+=r.x; v.y+=r.y; v.z+=r.z; v.w+=r.w;
    }
    ((float4*)(res + (size_t)bt*DM))[lane] = v;
    float s  = v.x+v.y+v.z+v.w;
    float ss = v.x*v.x+v.y*v.y+v.z*v.z+v.w*v.w;
#pragma unroll
    for(int m=1;m<64;m<<=1){ s += __shfl_xor(s,m); ss += __shfl_xor(ss,m); }
    float mean = s*(1.f/DM);
    float var  = ss*(1.f/DM) - mean*mean;
    float inv  = rsqrtf(var + 1e-5f);
    float4 wt = ((const float4*)w)[lane];
    float4 bs = ((const float4*)b)[lane];
    float4 o;
    o.x = (v.x-mean)*inv*wt.x + bs.x;
    o.y = (v.y-mean)*inv*wt.y + bs.y;
    o.z = (v.z-mean)*inv*wt.z + bs.z;
    o.w = (v.w-mean)*inv*wt.w + bs.w;
    ushort4 hh, ll;
    hh.x = f2bf(o.x); ll.x = f2bf(o.x - bf2f(hh.x));
    hh.y = f2bf(o.y); ll.y = f2bf(o.y - bf2f(hh.y));
    hh.z = f2bf(o.z); ll.z = f2bf(o.z - bf2f(hh.z));
    hh.w = f2bf(o.w); ll.w = f2bf(o.w - bf2f(hh.w));
    ((ushort4*)(hnhi + (size_t)bt*DM))[lane] = hh;
    ((ushort4*)(hnlo + (size_t)bt*DM))[lane] = ll;
}

// C[M][N] = A[M][K] @ Bw[N][K]^T via bf16 MFMA, hi/lo 3-term split (inproj)
template<int BM,int BN>
__global__ void __launch_bounds__(256) k_gemm_bf3(
    const unsigned short* __restrict__ Ahi, const unsigned short* __restrict__ Alo,
    const unsigned short* __restrict__ Bhi, const unsigned short* __restrict__ Blo,
    float* __restrict__ C, int M, int N, int K)
{
    constexpr int LDP = 40;
    constexpr int WM = BM/2, WN = BN/2;
    constexpr int MI_ = WM/16, NI_ = WN/16;
    __shared__ unsigned short sAh[BM*LDP], sAl[BM*LDP], sBh[BN*LDP], sBl[BN*LDP];
    int tid  = threadIdx.x;
    int wave = tid >> 6, lane = tid & 63;
    int wm0  = (wave >> 1) * WM, wn0 = (wave & 1) * WN;
    int m0   = blockIdx.y * BM, n0 = blockIdx.x * BN;
    int lr   = lane & 15;
    int kq   = (lane >> 4) * 8;
    int quad4 = (lane >> 4) * 4;

    f32x4 acc[MI_][NI_];
#pragma unroll
    for(int i=0;i<MI_;i++)
#pragma unroll
        for(int j=0;j<NI_;j++) acc[i][j] = (f32x4){0.f,0.f,0.f,0.f};

    for(int k0=0;k0<K;k0+=32){
#pragma unroll
        for(int i=tid;i<BM*4;i+=256){
            int r = i>>2, cg = (i&3)*8;
            size_t go = (size_t)(m0+r)*K + k0 + cg;
            *(float4*)(&sAh[r*LDP + cg]) = *(const float4*)(Ahi + go);
            *(float4*)(&sAl[r*LDP + cg]) = *(const float4*)(Alo + go);
        }
#pragma unroll
        for(int i=tid;i<BN*4;i+=256){
            int r = i>>2, cg = (i&3)*8;
            size_t go = (size_t)(n0+r)*K + k0 + cg;
            *(float4*)(&sBh[r*LDP + cg]) = *(const float4*)(Bhi + go);
            *(float4*)(&sBl[r*LDP + cg]) = *(const float4*)(Blo + go);
        }
        __syncthreads();
        bf16x8 ah[MI_], al[MI_], bh[NI_], bl[NI_];
#pragma unroll
        for(int mi=0;mi<MI_;mi++){
            int ro = (wm0 + mi*16 + lr)*LDP + kq;
            ah[mi] = *(const bf16x8*)(&sAh[ro]);
            al[mi] = *(const bf16x8*)(&sAl[ro]);
        }
#pragma unroll
        for(int ni=0;ni<NI_;ni++){
            int ro = (wn0 + ni*16 + lr)*LDP + kq;
            bh[ni] = *(const bf16x8*)(&sBh[ro]);
            bl[ni] = *(const bf16x8*)(&sBl[ro]);
        }
#pragma unroll
        for(int mi=0;mi<MI_;mi++)
#pragma unroll
            for(int ni=0;ni<NI_;ni++){
                acc[mi][ni] = __builtin_amdgcn_mfma_f32_16x16x32_bf16(ah[mi], bh[ni], acc[mi][ni], 0,0,0);
                acc[mi][ni] = __builtin_amdgcn_mfma_f32_16x16x32_bf16(ah[mi], bl[ni], acc[mi][ni], 0,0,0);
                acc[mi][ni] = __builtin_amdgcn_mfma_f32_16x16x32_bf16(al[mi], bh[ni], acc[mi][ni], 0,0,0);
            }
        __syncthreads();
    }
#pragma unroll
    for(int mi=0;mi<MI_;mi++)
#pragma unroll
        for(int ni=0;ni<NI_;ni++){
            int col = n0 + wn0 + ni*16 + lr;
#pragma unroll
            for(int r=0;r<4;r++){
                int row = m0 + wm0 + mi*16 + quad4 + r;
                C[(size_t)row*N + col] = acc[mi][ni][r];
            }
        }
}

// ---- outproj: same GEMM but A rows are packed (hi | lo<<16) uints from scan3 ----
template<int BM,int BN>
__global__ void __launch_bounds__(256) k_gemm_pk(
    const unsigned* __restrict__ Apk,
    const unsigned short* __restrict__ Bhi, const unsigned short* __restrict__ Blo,
    float* __restrict__ C, int M, int N, int K)
{
    constexpr int LDP = 40;
    constexpr int WM = BM/2, WN = BN/2;
    constexpr int MI_ = WM/16, NI_ = WN/16;
    __shared__ unsigned short sAh[BM*LDP], sAl[BM*LDP], sBh[BN*LDP], sBl[BN*LDP];
    int tid  = threadIdx.x;
    int wave = tid >> 6, lane = tid & 63;
    int wm0  = (wave >> 1) * WM, wn0 = (wave & 1) * WN;
    int m0   = blockIdx.y * BM, n0 = blockIdx.x * BN;
    int lr   = lane & 15;
    int kq   = (lane >> 4) * 8;
    int quad4 = (lane >> 4) * 4;

    f32x4 acc[MI_][NI_];
#pragma unroll
    for(int i=0;i<MI_;i++)
#pragma unroll
        for(int j=0;j<NI_;j++) acc[i][j] = (f32x4){0.f,0.f,0.f,0.f};

    for(int k0=0;k0<K;k0+=32){
        // A staging: unpack 32 packed uints/row; 2 threads per row, 16 uints each
#pragma unroll
        for(int i=tid;i<BM*2;i+=256){
            int r = i>>1, hf = (i&1)*16;
            const uint4* yp = (const uint4*)(Apk + (size_t)(m0+r)*K + k0 + hf);
#pragma unroll
            for(int q=0;q<2;q++){
                uint4 p = yp[q];
                union { bf16x8 v; unsigned short u[8]; } H, L;
                uint4 p2 = yp[q];
                H.u[0]=(unsigned short)p.x;  L.u[0]=(unsigned short)(p.x>>16);
                H.u[1]=(unsigned short)p.y;  L.u[1]=(unsigned short)(p.y>>16);
                H.u[2]=(unsigned short)p.z;  L.u[2]=(unsigned short)(p.z>>16);
                H.u[3]=(unsigned short)p.w;  L.u[3]=(unsigned short)(p.w>>16);
                (void)p2;
                // second half of the 8: next uint4 handled by loop iteration q
                *(ushort4*)(&sAh[r*LDP + hf + q*4]) = *(ushort4*)H.u;
                *(ushort4*)(&sAl[r*LDP + hf + q*4]) = *(ushort4*)L.u;
            }
            // remaining 8 uints (cols hf+8..hf+15)
#pragma unroll
            for(int q=2;q<4;q++){
                uint4 p = yp[q];
                union { ushort4 v; unsigned short u[4]; } H, L;
                H.u[0]=(unsigned short)p.x;  L.u[0]=(unsigned short)(p.x>>16);
                H.u[1]=(unsigned short)p.y;  L.u[1]=(unsigned short)(p.y>>16);
                H.u[2]=(unsigned short)p.z;  L.u[2]=(unsigned short)(p.z>>16);
                H.u[3]=(unsigned short)p.w;  L.u[3]=(unsigned short)(p.w>>16);
                *(ushort4*)(&sAh[r*LDP + hf + q*4]) = H.v;
                *(ushort4*)(&sAl[r*LDP + hf + q*4]) = L.v;
            }
        }
#pragma unroll
        for(int i=tid;i<BN*4;i+=256){
            int r = i>>2, cg = (i&3)*8;
            size_t go = (size_t)(n0+r)*K + k0 + cg;
            *(float4*)(&sBh[r*LDP + cg]) = *(const float4*)(Bhi + go);
            *(float4*)(&sBl[r*LDP + cg]) = *(const float4*)(Blo + go);
        }
        __syncthreads();
        bf16x8 ah[MI_], al[MI_], bh[NI_], bl[NI_];
#pragma unroll
        for(int mi=0;mi<MI_;mi++){
            int ro = (wm0 + mi*16 + lr)*LDP + kq;
            ah[mi] = *(const bf16x8*)(&sAh[ro]);
            al[mi] = *(const bf16x8*)(&sAl[ro]);
        }
#pragma unroll
        for(int ni=0;ni<NI_;ni++){
            int ro = (wn0 + ni*16 + lr)*LDP + kq;
            bh[ni] = *(const bf16x8*)(&sBh[ro]);
            bl[ni] = *(const bf16x8*)(&sBl[ro]);
        }
#pragma unroll
        for(int mi=0;mi<MI_;mi++)
#pragma unroll
            for(int ni=0;ni<NI_;ni++){
                acc[mi][ni] = __builtin_amdgcn_mfma_f32_16x16x32_bf16(ah[mi], bh[ni], acc[mi][ni], 0,0,0);
                acc[mi][ni] = __builtin_amdgcn_mfma_f32_16x16x32_bf16(ah[mi], bl[ni], acc[mi][ni], 0,0,0);
                acc[mi][ni] = __builtin_amdgcn_mfma_f32_16x16x32_bf16(al[mi], bh[ni], acc[mi][ni], 0,0,0);
            }
        __syncthreads();
    }
#pragma unroll
    for(int mi=0;mi<MI_;mi++)
#pragma unroll
        for(int ni=0;ni<NI_;ni++){
            int col = n0 + wn0 + ni*16 + lr;
#pragma unroll
            for(int r=0;r<4;r++){
                int row = m0 + wm0 + mi*16 + quad4 + r;
                C[(size_t)row*N + col] = acc[mi][ni][r];
            }
        }
}

// ---- conv+SiLU | xproj MFMA | dtproj ----
__global__ void __launch_bounds__(512) k_convxp2(
    const float* __restrict__ xz, const float* __restrict__ cw, const float* __restrict__ cb,
    const unsigned short* __restrict__ Bhi, const unsigned short* __restrict__ Blo,
    const float* __restrict__ dtW, const float* __restrict__ dtbias,
    float* __restrict__ xh, float* __restrict__ bc, float* __restrict__ dtO)
{
    __shared__ unsigned short sAh[16*520], sAl[16*520];
    __shared__ float dls[16*17];

    int tid = threadIdx.x;
    int wave = tid >> 6, lane = tid & 63;
    int lr = lane & 15, kq = (lane>>4)*8, quad4 = (lane>>4)*4;
    int m0 = blockIdx.x * LCH;
    int d  = tid;

    float xv[19];
    {
        int rbase = m0 - 3;
        bool mask0 = ((m0 & (T_-1)) == 0);
#pragma unroll
        for(int j=0;j<19;j++)
            xv[j] = (mask0 && j<3) ? 0.f : xz[(size_t)(rbase+j)*DX + d];
    }
    float4 w4 = *(const float4*)(cw + d*4);
    float bias = cb[d];
#pragma unroll
    for(int t=0;t<16;t++){
        float a = bias + w4.x*xv[t] + w4.y*xv[t+1] + w4.z*xv[t+2] + w4.w*xv[t+3];
        float v = a * sigmoidf_(a);
        xh[(size_t)(m0+t)*DI + d] = v;
        unsigned short hh = f2bf(v);
        sAh[t*520 + d] = hh;
        sAl[t*520 + d] = f2bf(v - bf2f(hh));
    }
    float wr_[16]; ld16(dtW + (size_t)d*16, wr_);
    float bsv = dtbias[d];
    __syncthreads();

    f32x4 acc = {0.f,0.f,0.f,0.f};
    if(wave < 3){
#pragma unroll 4
        for(int ks=0;ks<16;ks++){
            int ao = lr*520 + ks*32 + kq;
            bf16x8 ah = *(const bf16x8*)(&sAh[ao]);
            bf16x8 al = *(const bf16x8*)(&sAl[ao]);
            size_t wo = (size_t)(wave*16 + lr)*DI + ks*32 + kq;
            bf16x8 bh = *(const bf16x8*)(Bhi + wo);
            bf16x8 bl = *(const bf16x8*)(Blo + wo);
            acc = __builtin_amdgcn_mfma_f32_16x16x32_bf16(ah, bh, acc, 0,0,0);
            acc = __builtin_amdgcn_mfma_f32_16x16x32_bf16(ah, bl, acc, 0,0,0);
            acc = __builtin_amdgcn_mfma_f32_16x16x32_bf16(al, bh, acc, 0,0,0);
        }
        if(wave == 0){
#pragma unroll
            for(int r=0;r<4;r++) dls[(quad4+r)*17 + lr] = acc[r];
        } else if(wave == 1){
#pragma unroll
            for(int r=0;r<4;r++) bc[(size_t)(m0+quad4+r)*32 + lr] = acc[r];
        } else {
#pragma unroll
            for(int r=0;r<4;r++) bc[(size_t)(m0+quad4+r)*32 + 16 + lr] = acc[r];
        }
    }
    __syncthreads();

#pragma unroll
    for(int t=0;t<16;t++){
        float acc2 = bsv;
#pragma unroll
        for(int r=0;r<16;r++) acc2 += dls[t*17 + r]*wr_[r];
        float sp = fmaxf(acc2,0.f) + log1pf(__expf(-fabsf(acc2)));
        dtO[(size_t)(m0+t)*DI + d] = sp;
    }
}

// ---- scan pass-1 ----
__global__ void __launch_bounds__(256) k_scan1(const float* __restrict__ dt,
    const float* __restrict__ xh, const float* __restrict__ bc,
    const float* __restrict__ A_log, float* __restrict__ S, float* __restrict__ sdt){
    int d = blockIdx.x*256 + threadIdx.x;
    int c = blockIdx.y, b = blockIdx.z;
    float a_[16]; ld16(A_log + (size_t)d*16, a_);
#pragma unroll
    for(int n=0;n<16;n++) a_[n] = -__expf(a_[n]);
    float st_[16];
#pragma unroll
    for(int n=0;n<16;n++) st_[n] = 0.f;
    float sd = 0.f;
    int base = b*T_ + c*LCH;
#pragma unroll 4
    for(int t=0;t<LCH;t++){
        int bt = base + t;
        float dtv = dt[(size_t)bt*DI + d];
        float xhv = xh[(size_t)bt*DI + d];
        float bv[16]; ld16(bc + (size_t)bt*32, bv);
        float dx = dtv*xhv;
        sd += dtv;
#pragma unroll
        for(int n=0;n<16;n++) st_[n] = __expf(dtv*a_[n])*st_[n] + dx*bv[n];
    }
    st16(S + (((size_t)b*NC_ + c)*DI + d)*16, st_);
    sdt[((size_t)b*NC_ + c)*DI + d] = sd;
}

// ---- pass 2: inter-chunk scan ----
__global__ void k_scan2(const float* __restrict__ S, const float* __restrict__ sdt,
                        const float* __restrict__ A_log, float* __restrict__ Hinit){
    int g = blockIdx.x*256 + threadIdx.x;
    int b = g >> 13;
    int dn = g & 8191;
    int d = dn >> 4;
    float a = -__expf(A_log[dn]);
    float H = 0.f;
    for(int c=0;c<NC_;c++){
        size_t o = ((size_t)(b*NC_ + c))*8192 + dn;
        Hinit[o] = H;
        float sd = sdt[(size_t)(b*NC_ + c)*DI + d];
        H = __expf(sd*a)*H + S[o];
    }
}

// ---- scan pass-3: replay + gate, packed Y out ----
__global__ void __launch_bounds__(256) k_scan3(
    const float* __restrict__ dt, const float* __restrict__ xh, const float* __restrict__ xz,
    const float* __restrict__ bc, const float* __restrict__ A_log, const float* __restrict__ Dpar,
    const float* __restrict__ Hinit, unsigned* __restrict__ Y)
{
    __shared__ float sbc[16*36];
    int tid = threadIdx.x;
    int c = blockIdx.y, b = blockIdx.z;
    int m0 = b*T_ + c*LCH;
    if(tid < 128){
        int t = tid >> 3, s = tid & 7;
        *(float4*)(&sbc[t*36 + s*4]) = *(const float4*)(bc + (size_t)(m0+t)*32 + s*4);
    }
    __syncthreads();
    int d = blockIdx.x*256 + tid;
    float a_[16]; ld16(A_log + (size_t)d*16, a_);
#pragma unroll
    for(int n=0;n<16;n++) a_[n] = -__expf(a_[n]);
    float st_[16]; ld16(Hinit + (((size_t)b*NC_ + c)*DI + d)*16, st_);
    float Dp = Dpar[d];
#pragma unroll 4
    for(int t=0;t<LCH;t++){
        int bt = m0 + t;
        float dtv = dt[(size_t)bt*DI + d];
        float xhv = xh[(size_t)bt*DI + d];
        float bv[16]; ld16(&sbc[t*36], bv);
        float cv[16]; ld16(&sbc[t*36 + 16], cv);
        float dx = dtv*xhv;
        float y = 0.f;
#pragma unroll
        for(int n=0;n<16;n++){
            st_[n] = __expf(dtv*a_[n])*st_[n] + dx*bv[n];
            y += st_[n]*cv[n];
        }
        float zv = xz[(size_t)bt*DX + DI + d];
        y += Dp*xhv;
        y = y * zv * sigmoidf_(zv);
        unsigned short hh = f2bf(y);
        unsigned short ll = f2bf(y - bf2f(hh));
        Y[(size_t)bt*DI + d] = (unsigned)hh | ((unsigned)ll << 16);
    }
}

// out[bt] = dot(h[bt, :256], out_W)
__global__ void k_outw(const float* __restrict__ h, const float* __restrict__ ow,
                       float* __restrict__ out){
    int wv = threadIdx.x >> 6, lane = threadIdx.x & 63;
    int bt = blockIdx.x*4 + wv;
    float4 v = ((const float4*)(h + (size_t)bt*DM))[lane];
    float4 w = ((const float4*)ow)[lane];
    float s = v.x*w.x + v.y*w.y + v.z*w.z + v.w*w.w;
#pragma unroll
    for(int m=1;m<64;m<<=1) s += __shfl_xor(s,m);
    if(lane==0) out[bt] = s;
}

extern "C" void kernel_launch(void* const* d_in, const int* in_sizes, int n_in,
                              void* d_out, int out_size, void* d_ws, size_t ws_size,
                              hipStream_t stream){
    const float* x_src    = (const float*)d_in[0];
    const float* in_W     = (const float*)d_in[2];
    const float* norm_w   = (const float*)d_in[3];
    const float* norm_b   = (const float*)d_in[4];
    const float* inproj_W = (const float*)d_in[5];
    const float* conv_w   = (const float*)d_in[6];
    const float* conv_b   = (const float*)d_in[7];
    const float* xproj_W  = (const float*)d_in[8];
    const float* dtproj_W = (const float*)d_in[9];
    const float* dtproj_b = (const float*)d_in[10];
    const float* A_log    = (const float*)d_in[11];
    const float* D_param  = (const float*)d_in[12];
    const float* outproj_W= (const float*)d_in[13];
    const float* out_W    = (const float*)d_in[14];

    float* ws  = (float*)d_ws;
    float* h    = ws;                        // BT*DM
    float* res  = h    + (size_t)BT_*DM;     // BT*DM
    float* xz   = res  + (size_t)BT_*DM;     // BT*DX
    float* xh   = xz   + (size_t)BT_*DX;     // BT*DI
    float* bcb  = xh   + (size_t)BT_*DI;     // BT*32
    float* dtb  = bcb  + (size_t)BT_*32;     // BT*DI
    float* sdtb = dtb  + (size_t)BT_*DI;     // B*NC*DI
    float* Sbuf = sdtb + (size_t)B_*NC_*DI;  // B*NC*DI*16
    float* Hbuf = Sbuf + (size_t)B_*NC_*DI*DS_;
    unsigned short* us = (unsigned short*)(Hbuf + (size_t)B_*NC_*DI*DS_);
    unsigned short* WhiIn  = us;                                  // NL*DX*DM
    unsigned short* WloIn  = WhiIn  + (size_t)NL*DX*DM;
    unsigned short* WhiOut = WloIn  + (size_t)NL*DX*DM;           // NL*DM*DI
    unsigned short* WloOut = WhiOut + (size_t)NL*DM*DI;
    unsigned short* WhiXp  = WloOut + (size_t)NL*DM*DI;           // NL*NO*DI
    unsigned short* WloXp  = WhiXp  + (size_t)NL*NO_*DI;
    unsigned short* hnhi   = WloXp  + (size_t)NL*NO_*DI;          // BT*DM
    unsigned short* hnlo   = hnhi   + (size_t)BT_*DM;
    unsigned*       ybuf   = (unsigned*)(hnlo + (size_t)BT_*DM);  // BT*DI

    k_cvtW<<<(NL*DX*DM/4 + 255)/256, 256, 0, stream>>>(inproj_W,  WhiIn,  WloIn,  NL*DX*DM/4);
    k_cvtW<<<(NL*DM*DI/4 + 255)/256, 256, 0, stream>>>(outproj_W, WhiOut, WloOut, NL*DM*DI/4);
    k_cvtW<<<(NL*NO_*DI/4 + 255)/256, 256, 0, stream>>>(xproj_W, WhiXp, WloXp, NL*NO_*DI/4);
    k_ingemm<<<BT_*DM/256, 256, 0, stream>>>(x_src, in_W, h);
    for(int i=0;i<NL;i++){
        k_resln<<<BT_/4, 256, 0, stream>>>(h, res, hnhi, hnlo, norm_w + i*DM, norm_b + i*DM, i>0 ? 1 : 0);
        k_gemm_bf3<128,128><<<dim3(DX/128, BT_/128), 256, 0, stream>>>(
            hnhi, hnlo, WhiIn + (size_t)i*DX*DM, WloIn + (size_t)i*DX*DM, xz, BT_, DX, DM);
        k_convxp2<<<BT_/LCH, 512, 0, stream>>>(xz, conv_w + i*DI*4, conv_b + i*DI,
            WhiXp + (size_t)i*NO_*DI, WloXp + (size_t)i*NO_*DI,
            dtproj_W + (size_t)i*DI*DR_, dtproj_b + i*DI, xh, bcb, dtb);
        k_scan1<<<dim3(2, NC_, B_), 256, 0, stream>>>(dtb, xh, bcb,
            A_log + (size_t)i*DI*DS_, Sbuf, sdtb);
        k_scan2<<<B_*DI*DS_/256, 256, 0, stream>>>(Sbuf, sdtb, A_log + (size_t)i*DI*DS_, Hbuf);
        k_scan3<<<dim3(2, NC_, B_), 256, 0, stream>>>(dtb, xh, xz, bcb, A_log + (size_t)i*DI*DS_,
            D_param + i*DI, Hbuf, ybuf);
        k_gemm_pk<128,64><<<dim3(DM/64, BT_/128), 256, 0, stream>>>(
            ybuf, WhiOut + (size_t)i*DM*DI, WloOut + (size_t)i*DM*DI, h, BT_, DM, DI);
    }
    k_outw<<<BT_/4, 256, 0, stream>>>(h, out_W, (float*)d_out);
}